// Round 1
// baseline (44.294 us; speedup 1.0000x reference)
//
#include <hip/hip_runtime.h>
#include <hip/hip_bf16.h>

// Block-sparse (block-diagonal) attention, MI355X gfx950.
// Shapes: q,k,v,out = [4,16,4096,64] fp32; BLOCK_SIZE=64, HEAD_DIM=64.
// One wave (64 threads) per 64x64 attention block; 4096 blocks total.
// Each block's Q/K/V tile is a contiguous 64*64 fp32 chunk in memory.

typedef __attribute__((ext_vector_type(8))) __bf16 bf16x8;
typedef __attribute__((ext_vector_type(4))) float f32x4;

__global__ __launch_bounds__(64, 4)
void sparse_attn_kernel(const float* __restrict__ q,
                        const float* __restrict__ k,
                        const float* __restrict__ v,
                        float* __restrict__ out) {
  // P matrix staged as bf16, row stride 72 (=144B: 16B-aligned, bank-friendly)
  __shared__ __bf16 Plds[64 * 72];

  const int l   = threadIdx.x;
  const int r16 = l & 15;   // 0..15
  const int q4  = l >> 4;   // 0..3
  const long long base = (long long)blockIdx.x * 4096;

  const float* __restrict__ Qp = q + base;
  const float* __restrict__ Kp = k + base;
  const float* __restrict__ Vp = v + base;
  float* __restrict__ Op = out + base;

  constexpr float kScale = 0.125f;  // 1/sqrt(64)

  // ---------------- Phase 1: S = Q * K^T (64x64) ----------------
  // mfma_f32_16x16x32_bf16 layouts:
  //   A: row = l&15,  k = 8*(l>>4) + t   (8 contiguous k)
  //   B: col = l&15,  k = 8*(l>>4) + t   (reads K row-major like A: B^T GEMM)
  //   C/D: col = l&15, row = 4*(l>>4) + reg
  f32x4 acc[4][4];
#pragma unroll
  for (int i = 0; i < 4; ++i)
#pragma unroll
    for (int j = 0; j < 4; ++j)
      acc[i][j] = (f32x4){0.f, 0.f, 0.f, 0.f};

  bf16x8 aQ[4][2];
#pragma unroll
  for (int i = 0; i < 4; ++i) {
#pragma unroll
    for (int kk = 0; kk < 2; ++kk) {
      const float* p = Qp + (i * 16 + r16) * 64 + kk * 32 + q4 * 8;
      f32x4 lo = *(const f32x4*)p;
      f32x4 hi = *(const f32x4*)(p + 4);
      bf16x8 f;
      f[0] = (__bf16)lo[0]; f[1] = (__bf16)lo[1];
      f[2] = (__bf16)lo[2]; f[3] = (__bf16)lo[3];
      f[4] = (__bf16)hi[0]; f[5] = (__bf16)hi[1];
      f[6] = (__bf16)hi[2]; f[7] = (__bf16)hi[3];
      aQ[i][kk] = f;
    }
  }

#pragma unroll
  for (int j = 0; j < 4; ++j) {
#pragma unroll
    for (int kk = 0; kk < 2; ++kk) {
      const float* p = Kp + (j * 16 + r16) * 64 + kk * 32 + q4 * 8;
      f32x4 lo = *(const f32x4*)p;
      f32x4 hi = *(const f32x4*)(p + 4);
      bf16x8 bK;
      bK[0] = (__bf16)lo[0]; bK[1] = (__bf16)lo[1];
      bK[2] = (__bf16)lo[2]; bK[3] = (__bf16)lo[3];
      bK[4] = (__bf16)hi[0]; bK[5] = (__bf16)hi[1];
      bK[6] = (__bf16)hi[2]; bK[7] = (__bf16)hi[3];
#pragma unroll
      for (int i = 0; i < 4; ++i)
        acc[i][j] = __builtin_amdgcn_mfma_f32_16x16x32_bf16(aQ[i][kk], bK,
                                                            acc[i][j], 0, 0, 0);
    }
  }

  // ---------------- Phase 2: row softmax (block-local, no online needed) ----
  // Lane holds S[row][col] with row = i*16 + 4*q4 + r, col = j*16 + r16.
  // Row reduce = 4 in-register (over j) + shfl_xor over the 16 col lanes.
#pragma unroll
  for (int i = 0; i < 4; ++i) {
#pragma unroll
    for (int r = 0; r < 4; ++r) {
      float s0 = acc[i][0][r] * kScale;
      float s1 = acc[i][1][r] * kScale;
      float s2 = acc[i][2][r] * kScale;
      float s3 = acc[i][3][r] * kScale;
      float m = fmaxf(fmaxf(s0, s1), fmaxf(s2, s3));
      m = fmaxf(m, __shfl_xor(m, 1));
      m = fmaxf(m, __shfl_xor(m, 2));
      m = fmaxf(m, __shfl_xor(m, 4));
      m = fmaxf(m, __shfl_xor(m, 8));
      float p0 = __expf(s0 - m);
      float p1 = __expf(s1 - m);
      float p2 = __expf(s2 - m);
      float p3 = __expf(s3 - m);
      float sum = (p0 + p1) + (p2 + p3);
      sum += __shfl_xor(sum, 1);
      sum += __shfl_xor(sum, 2);
      sum += __shfl_xor(sum, 4);
      sum += __shfl_xor(sum, 8);
      float rinv = __fdividef(1.0f, sum);
      const int row = i * 16 + q4 * 4 + r;
      Plds[row * 72 + 0 * 16 + r16] = (__bf16)(p0 * rinv);
      Plds[row * 72 + 1 * 16 + r16] = (__bf16)(p1 * rinv);
      Plds[row * 72 + 2 * 16 + r16] = (__bf16)(p2 * rinv);
      Plds[row * 72 + 3 * 16 + r16] = (__bf16)(p3 * rinv);
    }
  }
  __syncthreads();  // single wave: cheap; orders P writes before reads

  // ---------------- Phase 3: O = P * V ----------------
  // A from Plds (contiguous 8 bf16 = one ds_read_b128 per fragment).
  // B from V direct global: V[key][d], lane reads 8 strided scalars.
  f32x4 oacc[4][4];
#pragma unroll
  for (int i = 0; i < 4; ++i)
#pragma unroll
    for (int j = 0; j < 4; ++j)
      oacc[i][j] = (f32x4){0.f, 0.f, 0.f, 0.f};

#pragma unroll
  for (int kk = 0; kk < 2; ++kk) {
    bf16x8 bV[4];
#pragma unroll
    for (int j = 0; j < 4; ++j) {
      const float* vp = Vp + (kk * 32 + q4 * 8) * 64 + j * 16 + r16;
      bf16x8 f;
#pragma unroll
      for (int t = 0; t < 8; ++t) f[t] = (__bf16)vp[t * 64];
      bV[j] = f;
    }
#pragma unroll
    for (int i = 0; i < 4; ++i) {
      const bf16x8 aP =
          *(const bf16x8*)(Plds + (i * 16 + r16) * 72 + kk * 32 + q4 * 8);
#pragma unroll
      for (int j = 0; j < 4; ++j)
        oacc[i][j] = __builtin_amdgcn_mfma_f32_16x16x32_bf16(aP, bV[j],
                                                             oacc[i][j], 0, 0, 0);
    }
  }

  // ---------------- Output write ----------------
#pragma unroll
  for (int i = 0; i < 4; ++i) {
#pragma unroll
    for (int r = 0; r < 4; ++r) {
      const int row = i * 16 + q4 * 4 + r;
#pragma unroll
      for (int j = 0; j < 4; ++j)
        Op[row * 64 + j * 16 + r16] = oacc[i][j][r];
    }
  }
}

extern "C" void kernel_launch(void* const* d_in, const int* in_sizes, int n_in,
                              void* d_out, int out_size, void* d_ws, size_t ws_size,
                              hipStream_t stream) {
  const float* q = (const float*)d_in[0];
  const float* k = (const float*)d_in[1];
  const float* v = (const float*)d_in[2];
  float* o = (float*)d_out;
  const int nblocks = in_sizes[0] / (64 * 64);  // 4096 for [4,16,4096,64]
  sparse_attn_kernel<<<dim3(nblocks), dim3(64), 0, stream>>>(q, k, v, o);
}